// Round 12
// baseline (7426.094 us; speedup 1.0000x reference)
//
#include <hip/hip_runtime.h>

// GRU: B=256, T=512, F=256, H=512, C=10  (MI355X / gfx950)
// Round 12 = Round 11's 4-set 8-phase pipeline with the topology bug fixed:
// 4 groups x 64 rows (= 256 = B, was 8x64=512 -> OOB crash), groups XCD-local
// on XCDs 0..3; XCDs 4..7 all burners. 4 rotating LDS bufs (64KB, known-good
// size): phase k reads buf k&3, writes buf (k+1)&3 (no WAR race given
// per-phase barriers). Verify-ahead flags: pre-read one phase early, verify
// (register compare in steady state) BEFORE tile loads. Burners: R9 loud
// cadence. xproj precomputed; h-part weights in registers.

#define BB 256
#define TT 512
#define FF 256
#define HH 512
#define HX 1536
#define GROUP_WGS 8
#define NGRP 4

typedef short short8 __attribute__((ext_vector_type(8)));
typedef short short4v __attribute__((ext_vector_type(4)));
typedef float float4v __attribute__((ext_vector_type(4)));
typedef unsigned long long u64;

// ws layout (bytes)
#define WFRAG_OFF 0
#define WFRAG_BYTES (32 * 3 * 24 * 64 * 8 * 2)            // 2,359,296
#define HBUF_OFF (WFRAG_OFF + WFRAG_BYTES)                 // bf16 h   [256][512]
#define RHBUF_OFF (HBUF_OFF + BB * HH * 2)                 // bf16 r*h [256][512]
#define HFIN_OFF (RHBUF_OFF + BB * HH * 2)                 // f32 h_final
#define CTRL_OFF (HFIN_OFF + BB * HH * 4)                  // claims + done + flags
#define CTRL_BYTES 16384
#define XBASE_OFF (CTRL_OFF + CTRL_BYTES)
#define XB_BYTES ((size_t)BB * TT * FF * 2)                // 67 MB (mode 1)
#define XPROJ_BYTES ((size_t)BB * TT * HX * 2)             // 402 MB (mode 2)
#define WS_M2 ((size_t)XBASE_OFF + XPROJ_BYTES)
#define WS_M1 ((size_t)XBASE_OFF + XB_BYTES)

__device__ __forceinline__ short f2bf(float f) {
  unsigned u = __builtin_bit_cast(unsigned, f);
  u += 0x7fffu + ((u >> 16) & 1u);            // RNE to bf16
  return (short)(u >> 16);
}
__device__ __forceinline__ float bf2f(unsigned short u) {
  return __builtin_bit_cast(float, (unsigned)u << 16);
}
__device__ __forceinline__ float sigm(float v) { return 1.0f / (1.0f + __expf(-v)); }
__device__ __forceinline__ float tanh_(float v) { return 2.0f / (1.0f + __expf(-2.0f * v)) - 1.0f; }
__device__ __forceinline__ float4v mfma_bf16(short8 a, short8 b, float4v c) {
  return __builtin_amdgcn_mfma_f32_16x16x32_bf16(a, b, c, 0, 0, 0);
}

// ---- weight prep: f32 [768][512] -> bf16 MFMA B-fragments ----
__global__ void prep_w(const float* __restrict__ Wz, const float* __restrict__ Wr,
                       const float* __restrict__ Wh, short* __restrict__ wfrag) {
  int id = blockIdx.x * 256 + threadIdx.x;     // 576*256 == 32*3*24*64
  int lane = id & 63;
  int rest = id >> 6;
  int kk = rest % 24;
  int gc = rest / 24;
  int g = gc % 3;
  int cb = gc / 3;
  if (cb >= 32) return;
  const float* W = (g == 0) ? Wz : ((g == 1) ? Wr : Wh);
  int n = cb * 16 + (lane & 15);
  int kbase = kk * 32 + (lane >> 4) * 8;
  short8 v;
#pragma unroll
  for (int j = 0; j < 8; ++j) v[j] = f2bf(W[(size_t)(kbase + j) * HH + n]);
  *(((short8*)wfrag) + id) = v;
}

// ---- x prep (mode 1 fallback): f32 -> bf16 ----
__global__ void xprep(const float* __restrict__ x, short* __restrict__ xb) {
  size_t i = (size_t)blockIdx.x * 256 + threadIdx.x;
  const float4v* src = (const float4v*)x;
  float4v a = src[i * 2], b = src[i * 2 + 1];
  short8 v;
  v[0] = f2bf(a[0]); v[1] = f2bf(a[1]); v[2] = f2bf(a[2]); v[3] = f2bf(a[3]);
  v[4] = f2bf(b[0]); v[5] = f2bf(b[1]); v[6] = f2bf(b[2]); v[7] = f2bf(b[3]);
  *(((short8*)xb) + i) = v;
}

// ---- xproj GEMM (mode 2): [BT,256] @ x-part weights -> bf16 [BT][3*512], bias folded ----
__global__ __launch_bounds__(256) void xproj_gemm(
    const float* __restrict__ x, const short* __restrict__ wfrag,
    const float* __restrict__ bz, const float* __restrict__ br,
    const float* __restrict__ bh, short* __restrict__ xp) {
  const int w = threadIdx.x >> 6, l = threadIdx.x & 63;
  const int l15 = l & 15, lhi = l >> 4;
  const size_t row0 = (size_t)blockIdx.x * 64 + w * 16;
  const float* xl = x + (row0 + l15) * FF + lhi * 8;
  short8 xf[8];
#pragma unroll
  for (int kx = 0; kx < 8; ++kx) {
    float4v a = *(const float4v*)(xl + kx * 32);
    float4v b2 = *(const float4v*)(xl + kx * 32 + 4);
    short8 v;
    v[0] = f2bf(a[0]); v[1] = f2bf(a[1]); v[2] = f2bf(a[2]); v[3] = f2bf(a[3]);
    v[4] = f2bf(b2[0]); v[5] = f2bf(b2[1]); v[6] = f2bf(b2[2]); v[7] = f2bf(b2[3]);
    xf[kx] = v;
  }
  const short8* wf = (const short8*)wfrag;
#pragma unroll 1
  for (int cb = 0; cb < 32; ++cb) {
#pragma unroll
    for (int g = 0; g < 3; ++g) {
      const float* bias = (g == 0) ? bz : ((g == 1) ? br : bh);
      float bv = bias[cb * 16 + l15];
      float4v acc = {bv, bv, bv, bv};
#pragma unroll
      for (int kx = 0; kx < 8; ++kx)
        acc = mfma_bf16(xf[kx], wf[((cb * 3 + g) * 24 + 16 + kx) * 64 + l], acc);
#pragma unroll
      for (int i = 0; i < 4; ++i)
        xp[(row0 + lhi * 4 + i) * HX + g * 512 + cb * 16 + l15] = f2bf(acc[i]);
    }
  }
}

// ---- flag primitives ----
__device__ __forceinline__ void wait_flags(const int* fl, int tgt) {
  const int* p = fl + (threadIdx.x & 31);
  int tries = 0;
  for (;;) {
    int v = __hip_atomic_load(p, __ATOMIC_RELAXED, __HIP_MEMORY_SCOPE_AGENT);
    if (!__any(v < tgt)) break;
    if (++tries > 64) __builtin_amdgcn_s_sleep(1);
  }
}
__device__ __forceinline__ int rdflag(const int* fl) {
  return __hip_atomic_load(fl + (threadIdx.x & 31), __ATOMIC_RELAXED,
                           __HIP_MEMORY_SCOPE_AGENT);
}

// L1-bypassing 16B fragment load (two relaxed agent-scope u64 loads)
__device__ __forceinline__ short8 ld_frag(const short* p) {
  const u64* q = (const u64*)p;
  u64 lo = __hip_atomic_load(q, __ATOMIC_RELAXED, __HIP_MEMORY_SCOPE_AGENT);
  u64 hi = __hip_atomic_load(q + 1, __ATOMIC_RELAXED, __HIP_MEMORY_SCOPE_AGENT);
  short4v l4 = __builtin_bit_cast(short4v, lo);
  short4v h4 = __builtin_bit_cast(short4v, hi);
  return __builtin_shufflevector(l4, h4, 0, 1, 2, 3, 4, 5, 6, 7);
}

// ================== 4-set 8-phase XCD-local GRU (mode 2) ==================
__global__ __launch_bounds__(256, 1) void gru4(
    const short* __restrict__ xp, const short* __restrict__ wfrag,
    short* __restrict__ hbuf, short* __restrict__ rhbuf,
    float* __restrict__ hfin, int* __restrict__ ctrl) {
  __shared__ short lds[4 * 8192];   // 4 rotating 16KB tile bufs
  __shared__ int s_slot, s_xcc;
  if (threadIdx.x == 0) {
    unsigned xcc;
    asm volatile("s_getreg_b32 %0, hwreg(HW_REG_XCC_ID)" : "=s"(xcc));
    xcc &= 7u;
    s_xcc = (int)xcc;
    s_slot = (xcc < NGRP) ? atomicAdd(ctrl + xcc * 16, 1) : 999;
  }
  __syncthreads();
  const int slot = s_slot;
  int* done = ctrl + 192;

  if (slot >= GROUP_WGS) {
    // burner (R9 loud cadence -- fastest measured)
    float a = (float)threadIdx.x;
    for (;;) {
#pragma unroll
      for (int i = 0; i < 512; ++i) a = __builtin_fmaf(a, 1.0000001f, 1.0f);
      asm volatile("" : "+v"(a));
      if (__hip_atomic_load(done, __ATOMIC_RELAXED, __HIP_MEMORY_SCOPE_AGENT) >= NGRP)
        break;
    }
    asm volatile("" :: "v"(a));
    return;
  }

  const int group = s_xcc, member = slot;
  const int tid = threadIdx.x;
  const int w = tid >> 6, l = tid & 63, l15 = l & 15, lhi = l >> 4;
  const int cbg = member * 4 + w, jc = cbg * 16;
  const int rb = group * 64;                  // 64 rows per group (4 sets x 16)
  const int dcol = jc + l15;

  // ---- weights (h-part) -> registers (192 VGPR) ----
  const short8* wf = (const short8*)wfrag;
  short8 wz[16], wr[16], wh[16];
#pragma unroll
  for (int kk = 0; kk < 16; ++kk) wz[kk] = wf[((cbg * 3 + 0) * 24 + kk) * 64 + l];
#pragma unroll
  for (int kk = 0; kk < 16; ++kk) wr[kk] = wf[((cbg * 3 + 1) * 24 + kk) * 64 + l];
#pragma unroll
  for (int kk = 0; kk < 16; ++kk) wh[kk] = wf[((cbg * 3 + 2) * 24 + kk) * 64 + l];

  // tile bases (16 rows x 512 each)
  const short* hS0 = hbuf + (size_t)(rb + 0) * HH;
  const short* hS1 = hbuf + (size_t)(rb + 16) * HH;
  const short* hS2 = hbuf + (size_t)(rb + 32) * HH;
  const short* hS3 = hbuf + (size_t)(rb + 48) * HH;
  const short* rhS0 = rhbuf + (size_t)(rb + 0) * HH;
  const short* rhS1 = rhbuf + (size_t)(rb + 16) * HH;
  const short* rhS2 = rhbuf + (size_t)(rb + 32) * HH;
  const short* rhS3 = rhbuf + (size_t)(rb + 48) * HH;

  // xproj pointers per set (rows rb+16s+lhi*4+i), gate offsets 0/512/1024
  const short* xp0[4]; const short* xp1[4]; const short* xp2[4]; const short* xp3[4];
#pragma unroll
  for (int i = 0; i < 4; ++i) {
    xp0[i] = xp + (size_t)(rb + 0 + lhi * 4 + i) * TT * HX + dcol;
    xp1[i] = xp + (size_t)(rb + 16 + lhi * 4 + i) * TT * HX + dcol;
    xp2[i] = xp + (size_t)(rb + 32 + lhi * 4 + i) * TT * HX + dcol;
    xp3[i] = xp + (size_t)(rb + 48 + lhi * 4 + i) * TT * HX + dcol;
  }

  // flags: 8 arrays x 32 ints per group
  int* fb = ctrl + 256 + group * 256;
  int* rhF0 = fb + 0, * rhF1 = fb + 32, * rhF2 = fb + 64, * rhF3 = fb + 96;
  int* hF0 = fb + 128, * hF1 = fb + 160, * hF2 = fb + 192, * hF3 = fb + 224;

  float4v h0 = {0,0,0,0}, h1 = {0,0,0,0}, h2 = {0,0,0,0}, h3 = {0,0,0,0};
  float4v z0, z1, z2, z3;
  float4v azx0, arx0, ahx0, azx1, arx1, ahx1, azx2, arx2, ahx2, azx3, arx3, ahx3;
#pragma unroll
  for (int i = 0; i < 4; ++i) {
    azx0[i] = bf2f(xp0[i][0]); arx0[i] = bf2f(xp0[i][512]); ahx0[i] = bf2f(xp0[i][1024]);
    azx1[i] = bf2f(xp1[i][0]); arx1[i] = bf2f(xp1[i][512]); ahx1[i] = bf2f(xp1[i][1024]);
    azx2[i] = bf2f(xp2[i][0]); arx2[i] = bf2f(xp2[i][512]); ahx2[i] = bf2f(xp2[i][1024]);
    azx3[i] = bf2f(xp3[i][0]); arx3[i] = bf2f(xp3[i][512]); ahx3[i] = bf2f(xp3[i][1024]);
  }

  short8 Ra[4], Rb[4];
  const short8 zero8 = {0,0,0,0,0,0,0,0};
#pragma unroll
  for (int i = 0; i < 4; ++i) { Ra[i] = zero8; Rb[i] = zero8; }
  int Va = 0, Vb = 0;

#define DSW(BUF, R)                                                          \
  { _Pragma("unroll") for (int i_ = 0; i_ < 4; ++i_) {                       \
      int idx_ = w * 2048 + i_ * 512 + l * 8;                                \
      idx_ ^= ((w * 4 + i_) & 7) << 3;                                       \
      *(short8*)&lds[(BUF) * 8192 + idx_] = (R)[i_]; } }
#define LDG(R, GSRC)                                                         \
  { _Pragma("unroll") for (int i_ = 0; i_ < 4; ++i_)                         \
      (R)[i_] = ld_frag((GSRC) + w * 2048 + i_ * 512 + l * 8); }
#define DSFRAG(BUF, KK)                                                      \
  (*(const short8*)&lds[(BUF) * 8192 +                                       \
      (((l15 << 9) | ((KK) * 32 + lhi * 8)) ^ ((l15 & 7) << 3))])
#define VERIFY(V, FL, TGT) { if (__any((V) < (TGT))) wait_flags(FL, TGT); }
#define ARR(FL, VAL)                                                         \
  { asm volatile("s_waitcnt vmcnt(0)" ::: "memory");                         \
    if (l == 0) __hip_atomic_store((FL) + cbg, VAL, __ATOMIC_RELAXED,        \
                                   __HIP_MEMORY_SCOPE_AGENT); }
#define P1C(BUF, AZX, ARX, Z, HL, S)                                         \
  { float4v az = AZX, ar = ARX;                                              \
    _Pragma("unroll") for (int kk = 0; kk < 16; ++kk) {                      \
      short8 a_ = DSFRAG(BUF, kk);                                           \
      az = mfma_bf16(a_, wz[kk], az); ar = mfma_bf16(a_, wr[kk], ar); }      \
    _Pragma("unroll") for (int i_ = 0; i_ < 4; ++i_) {                       \
      Z[i_] = sigm(az[i_]); float rv_ = sigm(ar[i_]);                        \
      rhbuf[(size_t)(rb + 16 * (S) + lhi * 4 + i_) * HH + dcol] =            \
          f2bf(rv_ * HL[i_]); } }
#define P2C(BUF, AHX, Z, HL, S)                                              \
  { float4v ah = AHX;                                                        \
    _Pragma("unroll") for (int kk = 0; kk < 16; ++kk)                        \
      ah = mfma_bf16(DSFRAG(BUF, kk), wh[kk], ah);                           \
    _Pragma("unroll") for (int i_ = 0; i_ < 4; ++i_) {                       \
      float hv_ = tanh_(ah[i_]);                                             \
      HL[i_] = (1.0f - Z[i_]) * HL[i_] + Z[i_] * hv_;                        \
      size_t dr_ = (size_t)(rb + 16 * (S) + lhi * 4 + i_) * HH + dcol;       \
      hbuf[dr_] = f2bf(HL[i_]);                                              \
      if (t + 1 == TT) hfin[dr_] = HL[i_]; } }
#define XPLD(XPP, AZX, ARX, AHX)                                             \
  if (t + 1 < TT) { size_t toff_ = (size_t)(t + 1) * HX;                     \
    _Pragma("unroll") for (int i_ = 0; i_ < 4; ++i_) {                       \
      AZX[i_] = bf2f(*(const unsigned short*)((XPP)[i_] + toff_));           \
      ARX[i_] = bf2f(*(const unsigned short*)((XPP)[i_] + toff_ + 512));     \
      AHX[i_] = bf2f(*(const unsigned short*)((XPP)[i_] + toff_ + 1024)); } }

  // prologue: buf0 = h0 zeros (consumed p0 of t=0); Rb holds h1 zeros for
  // p0's DSW(1). Va=Vb=0.
  for (int i = tid; i < 8192; i += 256) lds[i] = 0;
  __syncthreads();

#pragma unroll 1
  for (int t = 0; t < TT; ++t) {
    // ---- p0: P1(set0) reads buf0 ----
    VERIFY(Va, hF2, t); LDG(Ra, hS2); Vb = rdflag(hF3); DSW(1, Rb);
    __syncthreads();
    P1C(0, azx0, arx0, z0, h0, 0);
    ARR(rhF0, t + 1);
    // ---- p1: P1(set1) reads buf1 ----
    VERIFY(Vb, hF3, t); LDG(Rb, hS3); Va = rdflag(rhF0); DSW(2, Ra);
    __syncthreads();
    P1C(1, azx1, arx1, z1, h1, 1);
    ARR(rhF1, t + 1);
    // ---- p2: P1(set2) reads buf2 ----
    VERIFY(Va, rhF0, t + 1); LDG(Ra, rhS0); Vb = rdflag(rhF1); DSW(3, Rb);
    __syncthreads();
    P1C(2, azx2, arx2, z2, h2, 2);
    ARR(rhF2, t + 1);
    // ---- p3: P1(set3) reads buf3 ----
    VERIFY(Vb, rhF1, t + 1); LDG(Rb, rhS1); Va = rdflag(rhF2); DSW(0, Ra);
    __syncthreads();
    P1C(3, azx3, arx3, z3, h3, 3);
    ARR(rhF3, t + 1);
    // ---- p4: P2(set0) reads buf0 ----
    VERIFY(Va, rhF2, t + 1); LDG(Ra, rhS2); Vb = rdflag(rhF3); DSW(1, Rb);
    __syncthreads();
    P2C(0, ahx0, z0, h0, 0);
    ARR(hF0, t + 1);
    XPLD(xp0, azx0, arx0, ahx0);
    // ---- p5: P2(set1) reads buf1 ----
    VERIFY(Vb, rhF3, t + 1); LDG(Rb, rhS3); Va = rdflag(hF0); DSW(2, Ra);
    __syncthreads();
    P2C(1, ahx1, z1, h1, 1);
    ARR(hF1, t + 1);
    XPLD(xp1, azx1, arx1, ahx1);
    // ---- p6: P2(set2) reads buf2 ----
    VERIFY(Va, hF0, t + 1); LDG(Ra, hS0); Vb = rdflag(hF1); DSW(3, Rb);
    __syncthreads();
    P2C(2, ahx2, z2, h2, 2);
    ARR(hF2, t + 1);
    XPLD(xp2, azx2, arx2, ahx2);
    // ---- p7: P2(set3) reads buf3 ----
    VERIFY(Vb, hF1, t + 1); LDG(Rb, hS1); Va = rdflag(hF2); DSW(0, Ra);
    __syncthreads();
    P2C(3, ahx3, z3, h3, 3);
    ARR(hF3, t + 1);
    XPLD(xp3, azx3, arx3, ahx3);
  }

  if (member == 0 && tid == 0)
    __hip_atomic_fetch_add(done, 1, __ATOMIC_RELAXED, __HIP_MEMORY_SCOPE_AGENT);
#undef DSW
#undef LDG
#undef DSFRAG
#undef VERIFY
#undef ARR
#undef P1C
#undef P2C
#undef XPLD
}

// ================== fallback (modes 1/0): R8 kernel ==================
__device__ __forceinline__ void arrive_flag(int* fl, int wid, int val) {
  asm volatile("s_waitcnt vmcnt(0)" ::: "memory");
  if ((threadIdx.x & 63) == 0)
    __hip_atomic_store(fl + wid, val, __ATOMIC_RELAXED, __HIP_MEMORY_SCOPE_AGENT);
}
__device__ __forceinline__ void gate_phase1(const short* hb_lane,
    const short8* wz, const short8* wr, float4v azx, float4v arx,
    float bz, float br, float4v& z, float4v& rr) {
  short8 a[16];
#pragma unroll
  for (int kk = 0; kk < 16; ++kk) a[kk] = ld_frag(hb_lane + kk * 32);
  float4v az = azx, ar = arx;
#pragma unroll
  for (int kk = 0; kk < 16; ++kk) {
    az = mfma_bf16(a[kk], wz[kk], az);
    ar = mfma_bf16(a[kk], wr[kk], ar);
  }
#pragma unroll
  for (int i = 0; i < 4; ++i) {
    z[i] = sigm(az[i] + bz);
    rr[i] = sigm(ar[i] + br);
  }
}
__device__ __forceinline__ float4v gate_phase2(const short* rh_lane,
    const short8* wh, float4v ahx, float bh, float4v z, float4v h_loc) {
  short8 a[16];
#pragma unroll
  for (int kk = 0; kk < 16; ++kk) a[kk] = ld_frag(rh_lane + kk * 32);
  float4v ah = ahx;
#pragma unroll
  for (int kk = 0; kk < 16; ++kk)
    ah = mfma_bf16(a[kk], wh[kk], ah);
  float4v hn;
#pragma unroll
  for (int i = 0; i < 4; ++i) {
    float hv = tanh_(ah[i] + bh);
    hn[i] = (1.0f - z[i]) * h_loc[i] + z[i] * hv;
  }
  return hn;
}
template <bool XB>
__device__ __forceinline__ void load_xf(short8 (&xf)[8], const short* xb_l,
                                        const float* xf_l, int t) {
#pragma unroll
  for (int kx = 0; kx < 8; ++kx) {
    if constexpr (XB) {
      xf[kx] = *(const short8*)(xb_l + (size_t)t * FF + kx * 32);
    } else {
      const float* xl = xf_l + (size_t)t * FF;
      float4v a = *(const float4v*)(xl + kx * 32);
      float4v b2 = *(const float4v*)(xl + kx * 32 + 4);
      short8 v;
      v[0] = f2bf(a[0]); v[1] = f2bf(a[1]); v[2] = f2bf(a[2]); v[3] = f2bf(a[3]);
      v[4] = f2bf(b2[0]); v[5] = f2bf(b2[1]); v[6] = f2bf(b2[2]); v[7] = f2bf(b2[3]);
      xf[kx] = v;
    }
  }
}
__device__ __forceinline__ void prime_x(const short8 (&xf)[8],
    const short8* wz, const short8* wr, const short8* wh,
    float4v& azx, float4v& arx, float4v& ahx) {
  azx = (float4v){0.f, 0.f, 0.f, 0.f};
  arx = (float4v){0.f, 0.f, 0.f, 0.f};
  ahx = (float4v){0.f, 0.f, 0.f, 0.f};
#pragma unroll
  for (int kx = 0; kx < 8; ++kx) {
    azx = mfma_bf16(xf[kx], wz[16 + kx], azx);
    arx = mfma_bf16(xf[kx], wr[16 + kx], arx);
    ahx = mfma_bf16(xf[kx], wh[16 + kx], ahx);
  }
}
template <int XM>
__global__ __launch_bounds__(256, 1) void gru_kernel(
    const void* __restrict__ xv, const short* __restrict__ wfrag,
    short* __restrict__ hbuf, short* __restrict__ rhbuf,
    float* __restrict__ hfin, int* __restrict__ ctrl,
    const float* __restrict__ bzv, const float* __restrict__ brv,
    const float* __restrict__ bhv) {
  __shared__ int s_slot, s_xcc;
  if (threadIdx.x == 0) {
    unsigned xcc;
    asm volatile("s_getreg_b32 %0, hwreg(HW_REG_XCC_ID)" : "=s"(xcc));
    xcc &= 7u;
    s_xcc = (int)xcc;
    s_slot = atomicAdd(ctrl + xcc * 16, 1);
  }
  __syncthreads();
  const int slot = s_slot;
  if (slot >= GROUP_WGS) return;
  const int group = s_xcc;
  const int member = slot;
  const int tid = threadIdx.x;
  const int w = tid >> 6;
  const int l = tid & 63;
  const int l15 = l & 15;
  const int lhi = l >> 4;
  const int cbg = member * 4 + w;
  const int jc = cbg * 16;
  const int rbA = group * 32;
  const int rbB = rbA + 16;
  const short8* wf = (const short8*)wfrag;
  short8 wz[24], wr[24], wh[24];
#pragma unroll
  for (int kk = 0; kk < 24; ++kk) wz[kk] = wf[((cbg * 3 + 0) * 24 + kk) * 64 + l];
#pragma unroll
  for (int kk = 0; kk < 24; ++kk) wr[kk] = wf[((cbg * 3 + 1) * 24 + kk) * 64 + l];
#pragma unroll
  for (int kk = 0; kk < 24; ++kk) wh[kk] = wf[((cbg * 3 + 2) * 24 + kk) * 64 + l];
  const float bz = bzv[jc + l15], br = brv[jc + l15], bh = bhv[jc + l15];
  const int drowA = rbA + lhi * 4, drowB = rbB + lhi * 4;
  const int dcol = jc + l15;
  const short* hbA = hbuf + (size_t)(rbA + l15) * HH + lhi * 8;
  const short* hbB = hbuf + (size_t)(rbB + l15) * HH + lhi * 8;
  const short* rhA = rhbuf + (size_t)(rbA + l15) * HH + lhi * 8;
  const short* rhB = rhbuf + (size_t)(rbB + l15) * HH + lhi * 8;
  const float* xfA32 = (XM == 0) ? ((const float*)xv + (size_t)(rbA + l15) * TT * FF + lhi * 8) : nullptr;
  const float* xfB32 = (XM == 0) ? ((const float*)xv + (size_t)(rbB + l15) * TT * FF + lhi * 8) : nullptr;
  const short* xbA = (XM == 1) ? ((const short*)xv + (size_t)(rbA + l15) * TT * FF + lhi * 8) : nullptr;
  const short* xbB = (XM == 1) ? ((const short*)xv + (size_t)(rbB + l15) * TT * FF + lhi * 8) : nullptr;
  float4v h_locA = {0.f, 0.f, 0.f, 0.f}, h_locB = {0.f, 0.f, 0.f, 0.f};
  int* fb = ctrl + 256 + group * 256;
  int* rhAf = fb, * rhBf = fb + 32, * hAf = fb + 64, * hBf = fb + 96;
  float4v azxA, arxA, ahxA, azxB, arxB, ahxB;
  {
    short8 xf[8];
    load_xf<XM == 1>(xf, xbA, xfA32, 0);
    prime_x(xf, wz, wr, wh, azxA, arxA, ahxA);
    load_xf<XM == 1>(xf, xbB, xfB32, 0);
    prime_x(xf, wz, wr, wh, azxB, arxB, ahxB);
  }
#pragma unroll 1
  for (int t = 0; t < TT; ++t) {
    if (t) wait_flags(hAf, t);
    float4v zA, rrA;
    gate_phase1(hbA, wz, wr, azxA, arxA, bz, br, zA, rrA);
#pragma unroll
    for (int i = 0; i < 4; ++i)
      rhbuf[(size_t)(drowA + i) * HH + dcol] = f2bf(rrA[i] * h_locA[i]);
    arrive_flag(rhAf, cbg, t + 1);
    if (t) wait_flags(hBf, t);
    float4v zB, rrB;
    gate_phase1(hbB, wz, wr, azxB, arxB, bz, br, zB, rrB);
#pragma unroll
    for (int i = 0; i < 4; ++i)
      rhbuf[(size_t)(drowB + i) * HH + dcol] = f2bf(rrB[i] * h_locB[i]);
    arrive_flag(rhBf, cbg, t + 1);
    wait_flags(rhAf, t + 1);
    h_locA = gate_phase2(rhA, wh, ahxA, bh, zA, h_locA);
    if (t + 1 < TT) {
#pragma unroll
      for (int i = 0; i < 4; ++i)
        hbuf[(size_t)(drowA + i) * HH + dcol] = f2bf(h_locA[i]);
      arrive_flag(hAf, cbg, t + 1);
    } else {
#pragma unroll
      for (int i = 0; i < 4; ++i)
        hfin[(size_t)(drowA + i) * HH + dcol] = h_locA[i];
    }
    wait_flags(rhBf, t + 1);
    h_locB = gate_phase2(rhB, wh, ahxB, bh, zB, h_locB);
    if (t + 1 < TT) {
#pragma unroll
      for (int i = 0; i < 4; ++i)
        hbuf[(size_t)(drowB + i) * HH + dcol] = f2bf(h_locB[i]);
      arrive_flag(hBf, cbg, t + 1);
    } else {
#pragma unroll
      for (int i = 0; i < 4; ++i)
        hfin[(size_t)(drowB + i) * HH + dcol] = h_locB[i];
    }
    if (t + 1 < TT) {
      short8 xf[8];
      load_xf<XM == 1>(xf, xbA, xfA32, t + 1);
      prime_x(xf, wz, wr, wh, azxA, arxA, ahxA);
      load_xf<XM == 1>(xf, xbB, xfB32, t + 1);
      prime_x(xf, wz, wr, wh, azxB, arxB, ahxB);
    }
  }
}

// out[b, c] = h_final[b,:] @ fc_w[:,c] + fc_b[c]
__global__ void fc_kernel(const float* __restrict__ hfin, const float* __restrict__ fw,
                          const float* __restrict__ fb, float* __restrict__ out) {
  int b = blockIdx.x;
  int tid = threadIdx.x;  // 64
  float p[10];
#pragma unroll
  for (int c = 0; c < 10; ++c) p[c] = 0.f;
  for (int k = tid; k < HH; k += 64) {
    float hv = hfin[(size_t)b * HH + k];
#pragma unroll
    for (int c = 0; c < 10; ++c) p[c] += hv * fw[k * 10 + c];
  }
#pragma unroll
  for (int c = 0; c < 10; ++c) {
    float v = p[c];
    for (int off = 32; off > 0; off >>= 1) v += __shfl_down(v, off);
    if (tid == 0) out[b * 10 + c] = v + fb[c];
  }
}

extern "C" void kernel_launch(void* const* d_in, const int* in_sizes, int n_in,
                              void* d_out, int out_size, void* d_ws, size_t ws_size,
                              hipStream_t stream) {
  const float* x = (const float*)d_in[0];
  const float* Wz_w = (const float*)d_in[1];
  const float* Wz_b = (const float*)d_in[2];
  const float* Wr_w = (const float*)d_in[3];
  const float* Wr_b = (const float*)d_in[4];
  const float* Wh_w = (const float*)d_in[5];
  const float* Wh_b = (const float*)d_in[6];
  const float* fc_w = (const float*)d_in[7];
  const float* fc_b = (const float*)d_in[8];

  char* ws = (char*)d_ws;
  short* wfrag = (short*)(ws + WFRAG_OFF);
  short* hbuf = (short*)(ws + HBUF_OFF);
  short* rhbuf = (short*)(ws + RHBUF_OFF);
  float* hfin = (float*)(ws + HFIN_OFF);
  int* ctrl = (int*)(ws + CTRL_OFF);
  short* xbase = (short*)(ws + XBASE_OFF);

  // h0 = 0, claim + done + flag arrays = 0 (EVERY launch)
  hipMemsetAsync(hbuf, 0, BB * HH * 2, stream);
  hipMemsetAsync(ctrl, 0, CTRL_BYTES, stream);

  prep_w<<<576, 256, 0, stream>>>(Wz_w, Wr_w, Wh_w, wfrag);

  if (ws_size >= WS_M2) {
    xproj_gemm<<<BB * TT / 64, 256, 0, stream>>>(x, wfrag, Wz_b, Wr_b, Wh_b, xbase);
    gru4<<<256, 256, 0, stream>>>(xbase, wfrag, hbuf, rhbuf, hfin, ctrl);
  } else if (ws_size >= WS_M1) {
    xprep<<<(BB * TT * FF / 8) / 256, 256, 0, stream>>>(x, xbase);
    gru_kernel<1><<<256, 256, 0, stream>>>(xbase, wfrag, hbuf, rhbuf, hfin, ctrl,
                                           Wz_b, Wr_b, Wh_b);
  } else {
    gru_kernel<0><<<256, 256, 0, stream>>>(x, wfrag, hbuf, rhbuf, hfin, ctrl,
                                           Wz_b, Wr_b, Wh_b);
  }
  fc_kernel<<<BB, 64, 0, stream>>>(hfin, fc_w, fc_b, (float*)d_out);
}

// Round 13
// 5408.618 us; speedup vs baseline: 1.3730x; 1.3730x over previous
//
#include <hip/hip_runtime.h>

// GRU: B=256, T=512, F=256, H=512, C=10  (MI355X / gfx950)
// Round 13: 8 XCD-local groups x 2 sets (A/B) x 4 phases/step, re-sequenced:
//   DSW(prefetched); sync; compute+stores; vmcnt(0) ack; ARR(own flag,
//   BEFORE waits -> no deadlock); wait_all(others, own-slot skipped);
//   LDG(tile for p+2, 1.5 phases to land); XPLD at p2/p3.
// The single explicit vmcnt(0) sits BEFORE any loads are issued, so prefetch
// latency is never re-exposed (R4/R9/R12 all drained their own prefetch).
// Burners: R9 loud cadence. xproj precomputed; h-part weights in registers.

#define BB 256
#define TT 512
#define FF 256
#define HH 512
#define HX 1536
#define GROUP_WGS 8
#define NGRP 8

typedef short short8 __attribute__((ext_vector_type(8)));
typedef short short4v __attribute__((ext_vector_type(4)));
typedef float float4v __attribute__((ext_vector_type(4)));
typedef unsigned long long u64;
typedef unsigned short ushort;

// ws layout (bytes)
#define WFRAG_OFF 0
#define WFRAG_BYTES (32 * 3 * 24 * 64 * 8 * 2)            // 2,359,296
#define HBUF_OFF (WFRAG_OFF + WFRAG_BYTES)                 // bf16 h   [256][512]
#define RHBUF_OFF (HBUF_OFF + BB * HH * 2)                 // bf16 r*h [256][512]
#define HFIN_OFF (RHBUF_OFF + BB * HH * 2)                 // f32 h_final
#define CTRL_OFF (HFIN_OFF + BB * HH * 4)                  // claims + done + flags
#define CTRL_BYTES 16384
#define XBASE_OFF (CTRL_OFF + CTRL_BYTES)
#define XB_BYTES ((size_t)BB * TT * FF * 2)                // 67 MB (mode 1)
#define XPROJ_BYTES ((size_t)BB * TT * HX * 2)             // 402 MB (mode 2)
#define WS_M2 ((size_t)XBASE_OFF + XPROJ_BYTES)
#define WS_M1 ((size_t)XBASE_OFF + XB_BYTES)

__device__ __forceinline__ short f2bf(float f) {
  unsigned u = __builtin_bit_cast(unsigned, f);
  u += 0x7fffu + ((u >> 16) & 1u);            // RNE to bf16
  return (short)(u >> 16);
}
__device__ __forceinline__ float bf2f(ushort u) {
  return __builtin_bit_cast(float, (unsigned)u << 16);
}
__device__ __forceinline__ float sigm(float v) { return 1.0f / (1.0f + __expf(-v)); }
__device__ __forceinline__ float tanh_(float v) { return 2.0f / (1.0f + __expf(-2.0f * v)) - 1.0f; }
__device__ __forceinline__ float4v mfma_bf16(short8 a, short8 b, float4v c) {
  return __builtin_amdgcn_mfma_f32_16x16x32_bf16(a, b, c, 0, 0, 0);
}

// ---- weight prep: f32 [768][512] -> bf16 MFMA B-fragments ----
__global__ void prep_w(const float* __restrict__ Wz, const float* __restrict__ Wr,
                       const float* __restrict__ Wh, short* __restrict__ wfrag) {
  int id = blockIdx.x * 256 + threadIdx.x;     // 576*256 == 32*3*24*64
  int lane = id & 63;
  int rest = id >> 6;
  int kk = rest % 24;
  int gc = rest / 24;
  int g = gc % 3;
  int cb = gc / 3;
  if (cb >= 32) return;
  const float* W = (g == 0) ? Wz : ((g == 1) ? Wr : Wh);
  int n = cb * 16 + (lane & 15);
  int kbase = kk * 32 + (lane >> 4) * 8;
  short8 v;
#pragma unroll
  for (int j = 0; j < 8; ++j) v[j] = f2bf(W[(size_t)(kbase + j) * HH + n]);
  *(((short8*)wfrag) + id) = v;
}

// ---- x prep (mode 1 fallback): f32 -> bf16 ----
__global__ void xprep(const float* __restrict__ x, short* __restrict__ xb) {
  size_t i = (size_t)blockIdx.x * 256 + threadIdx.x;
  const float4v* src = (const float4v*)x;
  float4v a = src[i * 2], b = src[i * 2 + 1];
  short8 v;
  v[0] = f2bf(a[0]); v[1] = f2bf(a[1]); v[2] = f2bf(a[2]); v[3] = f2bf(a[3]);
  v[4] = f2bf(b[0]); v[5] = f2bf(b[1]); v[6] = f2bf(b[2]); v[7] = f2bf(b[3]);
  *(((short8*)xb) + i) = v;
}

// ---- xproj GEMM (mode 2): [BT,256] @ x-part weights -> bf16 [BT][3*512], bias folded ----
__global__ __launch_bounds__(256) void xproj_gemm(
    const float* __restrict__ x, const short* __restrict__ wfrag,
    const float* __restrict__ bz, const float* __restrict__ br,
    const float* __restrict__ bh, short* __restrict__ xp) {
  const int w = threadIdx.x >> 6, l = threadIdx.x & 63;
  const int l15 = l & 15, lhi = l >> 4;
  const size_t row0 = (size_t)blockIdx.x * 64 + w * 16;
  const float* xl = x + (row0 + l15) * FF + lhi * 8;
  short8 xf[8];
#pragma unroll
  for (int kx = 0; kx < 8; ++kx) {
    float4v a = *(const float4v*)(xl + kx * 32);
    float4v b2 = *(const float4v*)(xl + kx * 32 + 4);
    short8 v;
    v[0] = f2bf(a[0]); v[1] = f2bf(a[1]); v[2] = f2bf(a[2]); v[3] = f2bf(a[3]);
    v[4] = f2bf(b2[0]); v[5] = f2bf(b2[1]); v[6] = f2bf(b2[2]); v[7] = f2bf(b2[3]);
    xf[kx] = v;
  }
  const short8* wf = (const short8*)wfrag;
#pragma unroll 1
  for (int cb = 0; cb < 32; ++cb) {
#pragma unroll
    for (int g = 0; g < 3; ++g) {
      const float* bias = (g == 0) ? bz : ((g == 1) ? br : bh);
      float bv = bias[cb * 16 + l15];
      float4v acc = {bv, bv, bv, bv};
#pragma unroll
      for (int kx = 0; kx < 8; ++kx)
        acc = mfma_bf16(xf[kx], wf[((cb * 3 + g) * 24 + 16 + kx) * 64 + l], acc);
#pragma unroll
      for (int i = 0; i < 4; ++i)
        xp[(row0 + lhi * 4 + i) * HX + g * 512 + cb * 16 + l15] = f2bf(acc[i]);
    }
  }
}

// ---- flag primitives ----
// wait for all 32 wave-flags >= tgt, skipping our own slot (set just before)
__device__ __forceinline__ void wait_all(const int* fl, int tgt, int own) {
  const int li = threadIdx.x & 31;
  const int* p = fl + li;
  const bool self = (li == own);
  int tries = 0;
  for (;;) {
    int v = self ? tgt
                 : __hip_atomic_load(p, __ATOMIC_RELAXED, __HIP_MEMORY_SCOPE_AGENT);
    if (!__any(v < tgt)) break;
    if (++tries > 64) __builtin_amdgcn_s_sleep(1);
  }
}

// L1-bypassing 16B fragment load (two relaxed agent-scope u64 loads)
__device__ __forceinline__ short8 ld_frag(const short* p) {
  const u64* q = (const u64*)p;
  u64 lo = __hip_atomic_load(q, __ATOMIC_RELAXED, __HIP_MEMORY_SCOPE_AGENT);
  u64 hi = __hip_atomic_load(q + 1, __ATOMIC_RELAXED, __HIP_MEMORY_SCOPE_AGENT);
  short4v l4 = __builtin_bit_cast(short4v, lo);
  short4v h4 = __builtin_bit_cast(short4v, hi);
  return __builtin_shufflevector(l4, h4, 0, 1, 2, 3, 4, 5, 6, 7);
}

// ============ 2-set 4-phase XCD-local GRU, re-sequenced (mode 2) ============
__global__ __launch_bounds__(256, 1) void gru2p(
    const short* __restrict__ xp, const short* __restrict__ wfrag,
    short* __restrict__ hbuf, short* __restrict__ rhbuf,
    float* __restrict__ hfin, int* __restrict__ ctrl) {
  __shared__ short lds[4 * 8192];   // 4 rotating 16KB tile bufs
  __shared__ int s_slot, s_xcc;
  if (threadIdx.x == 0) {
    unsigned xcc;
    asm volatile("s_getreg_b32 %0, hwreg(HW_REG_XCC_ID)" : "=s"(xcc));
    xcc &= 7u;
    s_xcc = (int)xcc;
    s_slot = atomicAdd(ctrl + xcc * 16, 1);
  }
  __syncthreads();
  const int slot = s_slot;
  int* done = ctrl + 192;

  if (slot >= GROUP_WGS) {
    // burner (R9 loud cadence -- fastest measured)
    float a = (float)threadIdx.x;
    for (;;) {
#pragma unroll
      for (int i = 0; i < 512; ++i) a = __builtin_fmaf(a, 1.0000001f, 1.0f);
      asm volatile("" : "+v"(a));
      if (__hip_atomic_load(done, __ATOMIC_RELAXED, __HIP_MEMORY_SCOPE_AGENT) >= NGRP)
        break;
    }
    asm volatile("" :: "v"(a));
    return;
  }

  const int group = s_xcc, member = slot;
  const int tid = threadIdx.x;
  const int w = tid >> 6, l = tid & 63, l15 = l & 15, lhi = l >> 4;
  const int cbg = member * 4 + w, jc = cbg * 16;
  const int rb = group * 32;                  // 32 rows per group (2 sets x 16)
  const int dcol = jc + l15;

  // ---- weights (h-part) -> registers (192 VGPR) ----
  const short8* wf = (const short8*)wfrag;
  short8 wz[16], wr[16], wh[16];
#pragma unroll
  for (int kk = 0; kk < 16; ++kk) wz[kk] = wf[((cbg * 3 + 0) * 24 + kk) * 64 + l];
#pragma unroll
  for (int kk = 0; kk < 16; ++kk) wr[kk] = wf[((cbg * 3 + 1) * 24 + kk) * 64 + l];
#pragma unroll
  for (int kk = 0; kk < 16; ++kk) wh[kk] = wf[((cbg * 3 + 2) * 24 + kk) * 64 + l];

  const short* hS_A = hbuf + (size_t)(rb + 0) * HH;
  const short* hS_B = hbuf + (size_t)(rb + 16) * HH;
  const short* rhS_A = rhbuf + (size_t)(rb + 0) * HH;
  const short* rhS_B = rhbuf + (size_t)(rb + 16) * HH;

  const short* xpA[4];
  const short* xpB[4];
#pragma unroll
  for (int i = 0; i < 4; ++i) {
    xpA[i] = xp + (size_t)(rb + 0 + lhi * 4 + i) * TT * HX + dcol;
    xpB[i] = xp + (size_t)(rb + 16 + lhi * 4 + i) * TT * HX + dcol;
  }

  int* fb = ctrl + 256 + group * 256;
  int* rhFA = fb + 0, * rhFB = fb + 32, * hFA = fb + 64, * hFB = fb + 96;

  float4v hA = {0,0,0,0}, hB = {0,0,0,0};
  float4v zA, zB;
  ushort nzA[4], nrA[4], nhA[4], nzB[4], nrB[4], nhB[4];

  short8 Ra[4], Rb[4];
  const short8 zero8 = {0,0,0,0,0,0,0,0};
#pragma unroll
  for (int i = 0; i < 4; ++i) { Ra[i] = zero8; Rb[i] = zero8; }

#define MEMBAR asm volatile("" ::: "memory")
#define ACK asm volatile("s_waitcnt vmcnt(0)" ::: "memory")
#define ARR(FL, VAL)                                                         \
  { if (l == 0) __hip_atomic_store((FL) + cbg, VAL, __ATOMIC_RELAXED,        \
                                   __HIP_MEMORY_SCOPE_AGENT); }
#define DSW(BUF, R)                                                          \
  { _Pragma("unroll") for (int i_ = 0; i_ < 4; ++i_) {                       \
      int idx_ = w * 2048 + i_ * 512 + l * 8;                                \
      idx_ ^= ((w * 4 + i_) & 7) << 3;                                       \
      *(short8*)&lds[(BUF) * 8192 + idx_] = (R)[i_]; } }
#define LDG(R, GSRC)                                                         \
  { _Pragma("unroll") for (int i_ = 0; i_ < 4; ++i_)                         \
      (R)[i_] = ld_frag((GSRC) + w * 2048 + i_ * 512 + l * 8); }
#define DSFRAG(BUF, KK)                                                      \
  (*(const short8*)&lds[(BUF) * 8192 +                                       \
      (((l15 << 9) | ((KK) * 32 + lhi * 8)) ^ ((l15 & 7) << 3))])
#define P1C(BUF, NZ, NR, Z, HL, S)                                           \
  { float4v az, ar;                                                          \
    _Pragma("unroll") for (int i_ = 0; i_ < 4; ++i_) {                       \
      az[i_] = bf2f(NZ[i_]); ar[i_] = bf2f(NR[i_]); }                        \
    _Pragma("unroll") for (int kk = 0; kk < 16; ++kk) {                      \
      short8 a_ = DSFRAG(BUF, kk);                                           \
      az = mfma_bf16(a_, wz[kk], az); ar = mfma_bf16(a_, wr[kk], ar); }      \
    _Pragma("unroll") for (int i_ = 0; i_ < 4; ++i_) {                       \
      Z[i_] = sigm(az[i_]); float rv_ = sigm(ar[i_]);                        \
      rhbuf[(size_t)(rb + 16 * (S) + lhi * 4 + i_) * HH + dcol] =            \
          f2bf(rv_ * HL[i_]); } }
#define P2C(BUF, NH, Z, HL, S)                                               \
  { float4v ah;                                                              \
    _Pragma("unroll") for (int i_ = 0; i_ < 4; ++i_) ah[i_] = bf2f(NH[i_]);  \
    _Pragma("unroll") for (int kk = 0; kk < 16; ++kk)                        \
      ah = mfma_bf16(DSFRAG(BUF, kk), wh[kk], ah);                           \
    _Pragma("unroll") for (int i_ = 0; i_ < 4; ++i_) {                       \
      float hv_ = tanh_(ah[i_]);                                             \
      HL[i_] = (1.0f - Z[i_]) * HL[i_] + Z[i_] * hv_;                        \
      size_t dr_ = (size_t)(rb + 16 * (S) + lhi * 4 + i_) * HH + dcol;       \
      hbuf[dr_] = f2bf(HL[i_]);                                              \
      if (t + 1 == TT) hfin[dr_] = HL[i_]; } }
#define XPLD(XPP, NZ, NR, NH)                                                \
  { size_t toff_ = (size_t)(t + 1) * HX;                                     \
    _Pragma("unroll") for (int i_ = 0; i_ < 4; ++i_) {                       \
      NZ[i_] = *(const ushort*)((XPP)[i_] + toff_);                          \
      NR[i_] = *(const ushort*)((XPP)[i_] + toff_ + 512);                    \
      NH[i_] = *(const ushort*)((XPP)[i_] + toff_ + 1024); } }

  // ---- prologue: stage xproj(t=0) for both sets ----
  {
#pragma unroll
    for (int i = 0; i < 4; ++i) {
      nzA[i] = *(const ushort*)(xpA[i]);
      nrA[i] = *(const ushort*)(xpA[i] + 512);
      nhA[i] = *(const ushort*)(xpA[i] + 1024);
      nzB[i] = *(const ushort*)(xpB[i]);
      nrB[i] = *(const ushort*)(xpB[i] + 512);
      nhB[i] = *(const ushort*)(xpB[i] + 1024);
    }
  }

#pragma unroll 1
  for (int t = 0; t < TT; ++t) {
    const bool more = (t + 1 < TT);
    // ===== p0: P1A -- consume hA (buf0, Ra), produce rhA =====
    DSW(0, Ra);
    __syncthreads();
    P1C(0, nzA, nrA, zA, hA, 0);
    MEMBAR; ACK;                    // own rhA stores acked in LIC
    ARR(rhFA, t + 1);               // arrive BEFORE any wait (no deadlock)
    wait_all(rhFA, t + 1, cbg);     // others' p0 (overlaps their ack)
    LDG(Ra, rhS_A);                 // rhA tile: consumed at p2 (1.5 phases)
    // ===== p1: P1B =====
    DSW(1, Rb);
    __syncthreads();
    P1C(1, nzB, nrB, zB, hB, 1);
    MEMBAR; ACK;
    ARR(rhFB, t + 1);
    wait_all(rhFB, t + 1, cbg);
    LDG(Rb, rhS_B);
    // ===== p2: P2A -- consume rhA (buf2, Ra), produce hA =====
    DSW(2, Ra);
    __syncthreads();
    P2C(2, nhA, zA, hA, 0);
    MEMBAR; ACK;
    if (more) {
      ARR(hFA, t + 1);
      wait_all(hFA, t + 1, cbg);
      LDG(Ra, hS_A);                // hA tile for p0 of t+1
      XPLD(xpA, nzA, nrA, nhA);     // xproj(t+1) set A (drains next ACK)
    }
    // ===== p3: P2B =====
    DSW(3, Rb);
    __syncthreads();
    P2C(3, nhB, zB, hB, 1);
    MEMBAR; ACK;
    if (more) {
      ARR(hFB, t + 1);
      wait_all(hFB, t + 1, cbg);
      LDG(Rb, hS_B);
      XPLD(xpB, nzB, nrB, nhB);
    }
  }

  if (member == 0 && tid == 0)
    __hip_atomic_fetch_add(done, 1, __ATOMIC_RELAXED, __HIP_MEMORY_SCOPE_AGENT);
#undef MEMBAR
#undef ACK
#undef ARR
#undef DSW
#undef LDG
#undef DSFRAG
#undef P1C
#undef P2C
#undef XPLD
}

// ================== fallback (modes 1/0): R8 kernel ==================
__device__ __forceinline__ void wait_flags(const int* fl, int tgt) {
  const int* p = fl + (threadIdx.x & 31);
  for (;;) {
    int v = __hip_atomic_load(p, __ATOMIC_RELAXED, __HIP_MEMORY_SCOPE_AGENT);
    if (!__any(v < tgt)) break;
  }
}
__device__ __forceinline__ void arrive_flag(int* fl, int wid, int val) {
  asm volatile("s_waitcnt vmcnt(0)" ::: "memory");
  if ((threadIdx.x & 63) == 0)
    __hip_atomic_store(fl + wid, val, __ATOMIC_RELAXED, __HIP_MEMORY_SCOPE_AGENT);
}
__device__ __forceinline__ void gate_phase1(const short* hb_lane,
    const short8* wz, const short8* wr, float4v azx, float4v arx,
    float bz, float br, float4v& z, float4v& rr) {
  short8 a[16];
#pragma unroll
  for (int kk = 0; kk < 16; ++kk) a[kk] = ld_frag(hb_lane + kk * 32);
  float4v az = azx, ar = arx;
#pragma unroll
  for (int kk = 0; kk < 16; ++kk) {
    az = mfma_bf16(a[kk], wz[kk], az);
    ar = mfma_bf16(a[kk], wr[kk], ar);
  }
#pragma unroll
  for (int i = 0; i < 4; ++i) {
    z[i] = sigm(az[i] + bz);
    rr[i] = sigm(ar[i] + br);
  }
}
__device__ __forceinline__ float4v gate_phase2(const short* rh_lane,
    const short8* wh, float4v ahx, float bh, float4v z, float4v h_loc) {
  short8 a[16];
#pragma unroll
  for (int kk = 0; kk < 16; ++kk) a[kk] = ld_frag(rh_lane + kk * 32);
  float4v ah = ahx;
#pragma unroll
  for (int kk = 0; kk < 16; ++kk)
    ah = mfma_bf16(a[kk], wh[kk], ah);
  float4v hn;
#pragma unroll
  for (int i = 0; i < 4; ++i) {
    float hv = tanh_(ah[i] + bh);
    hn[i] = (1.0f - z[i]) * h_loc[i] + z[i] * hv;
  }
  return hn;
}
template <bool XB>
__device__ __forceinline__ void load_xf(short8 (&xf)[8], const short* xb_l,
                                        const float* xf_l, int t) {
#pragma unroll
  for (int kx = 0; kx < 8; ++kx) {
    if constexpr (XB) {
      xf[kx] = *(const short8*)(xb_l + (size_t)t * FF + kx * 32);
    } else {
      const float* xl = xf_l + (size_t)t * FF;
      float4v a = *(const float4v*)(xl + kx * 32);
      float4v b2 = *(const float4v*)(xl + kx * 32 + 4);
      short8 v;
      v[0] = f2bf(a[0]); v[1] = f2bf(a[1]); v[2] = f2bf(a[2]); v[3] = f2bf(a[3]);
      v[4] = f2bf(b2[0]); v[5] = f2bf(b2[1]); v[6] = f2bf(b2[2]); v[7] = f2bf(b2[3]);
      xf[kx] = v;
    }
  }
}
__device__ __forceinline__ void prime_x(const short8 (&xf)[8],
    const short8* wz, const short8* wr, const short8* wh,
    float4v& azx, float4v& arx, float4v& ahx) {
  azx = (float4v){0.f, 0.f, 0.f, 0.f};
  arx = (float4v){0.f, 0.f, 0.f, 0.f};
  ahx = (float4v){0.f, 0.f, 0.f, 0.f};
#pragma unroll
  for (int kx = 0; kx < 8; ++kx) {
    azx = mfma_bf16(xf[kx], wz[16 + kx], azx);
    arx = mfma_bf16(xf[kx], wr[16 + kx], arx);
    ahx = mfma_bf16(xf[kx], wh[16 + kx], ahx);
  }
}
template <int XM>
__global__ __launch_bounds__(256, 1) void gru_kernel(
    const void* __restrict__ xv, const short* __restrict__ wfrag,
    short* __restrict__ hbuf, short* __restrict__ rhbuf,
    float* __restrict__ hfin, int* __restrict__ ctrl,
    const float* __restrict__ bzv, const float* __restrict__ brv,
    const float* __restrict__ bhv) {
  __shared__ int s_slot, s_xcc;
  if (threadIdx.x == 0) {
    unsigned xcc;
    asm volatile("s_getreg_b32 %0, hwreg(HW_REG_XCC_ID)" : "=s"(xcc));
    xcc &= 7u;
    s_xcc = (int)xcc;
    s_slot = atomicAdd(ctrl + xcc * 16, 1);
  }
  __syncthreads();
  const int slot = s_slot;
  if (slot >= GROUP_WGS) return;
  const int group = s_xcc;
  const int member = slot;
  const int tid = threadIdx.x;
  const int w = tid >> 6;
  const int l = tid & 63;
  const int l15 = l & 15;
  const int lhi = l >> 4;
  const int cbg = member * 4 + w;
  const int jc = cbg * 16;
  const int rbA = group * 32;
  const int rbB = rbA + 16;
  const short8* wf = (const short8*)wfrag;
  short8 wz[24], wr[24], wh[24];
#pragma unroll
  for (int kk = 0; kk < 24; ++kk) wz[kk] = wf[((cbg * 3 + 0) * 24 + kk) * 64 + l];
#pragma unroll
  for (int kk = 0; kk < 24; ++kk) wr[kk] = wf[((cbg * 3 + 1) * 24 + kk) * 64 + l];
#pragma unroll
  for (int kk = 0; kk < 24; ++kk) wh[kk] = wf[((cbg * 3 + 2) * 24 + kk) * 64 + l];
  const float bz = bzv[jc + l15], br = brv[jc + l15], bh = bhv[jc + l15];
  const int drowA = rbA + lhi * 4, drowB = rbB + lhi * 4;
  const int dcol = jc + l15;
  const short* hbA = hbuf + (size_t)(rbA + l15) * HH + lhi * 8;
  const short* hbB = hbuf + (size_t)(rbB + l15) * HH + lhi * 8;
  const short* rhA = rhbuf + (size_t)(rbA + l15) * HH + lhi * 8;
  const short* rhB = rhbuf + (size_t)(rbB + l15) * HH + lhi * 8;
  const float* xfA32 = (XM == 0) ? ((const float*)xv + (size_t)(rbA + l15) * TT * FF + lhi * 8) : nullptr;
  const float* xfB32 = (XM == 0) ? ((const float*)xv + (size_t)(rbB + l15) * TT * FF + lhi * 8) : nullptr;
  const short* xbA = (XM == 1) ? ((const short*)xv + (size_t)(rbA + l15) * TT * FF + lhi * 8) : nullptr;
  const short* xbB = (XM == 1) ? ((const short*)xv + (size_t)(rbB + l15) * TT * FF + lhi * 8) : nullptr;
  float4v h_locA = {0.f, 0.f, 0.f, 0.f}, h_locB = {0.f, 0.f, 0.f, 0.f};
  int* fb = ctrl + 256 + group * 256;
  int* rhAf = fb, * rhBf = fb + 32, * hAf = fb + 64, * hBf = fb + 96;
  float4v azxA, arxA, ahxA, azxB, arxB, ahxB;
  {
    short8 xf[8];
    load_xf<XM == 1>(xf, xbA, xfA32, 0);
    prime_x(xf, wz, wr, wh, azxA, arxA, ahxA);
    load_xf<XM == 1>(xf, xbB, xfB32, 0);
    prime_x(xf, wz, wr, wh, azxB, arxB, ahxB);
  }
#pragma unroll 1
  for (int t = 0; t < TT; ++t) {
    if (t) wait_flags(hAf, t);
    float4v zA, rrA;
    gate_phase1(hbA, wz, wr, azxA, arxA, bz, br, zA, rrA);
#pragma unroll
    for (int i = 0; i < 4; ++i)
      rhbuf[(size_t)(drowA + i) * HH + dcol] = f2bf(rrA[i] * h_locA[i]);
    arrive_flag(rhAf, cbg, t + 1);
    if (t) wait_flags(hBf, t);
    float4v zB, rrB;
    gate_phase1(hbB, wz, wr, azxB, arxB, bz, br, zB, rrB);
#pragma unroll
    for (int i = 0; i < 4; ++i)
      rhbuf[(size_t)(drowB + i) * HH + dcol] = f2bf(rrB[i] * h_locB[i]);
    arrive_flag(rhBf, cbg, t + 1);
    wait_flags(rhAf, t + 1);
    h_locA = gate_phase2(rhA, wh, ahxA, bh, zA, h_locA);
    if (t + 1 < TT) {
#pragma unroll
      for (int i = 0; i < 4; ++i)
        hbuf[(size_t)(drowA + i) * HH + dcol] = f2bf(h_locA[i]);
      arrive_flag(hAf, cbg, t + 1);
    } else {
#pragma unroll
      for (int i = 0; i < 4; ++i)
        hfin[(size_t)(drowA + i) * HH + dcol] = h_locA[i];
    }
    wait_flags(rhBf, t + 1);
    h_locB = gate_phase2(rhB, wh, ahxB, bh, zB, h_locB);
    if (t + 1 < TT) {
#pragma unroll
      for (int i = 0; i < 4; ++i)
        hbuf[(size_t)(drowB + i) * HH + dcol] = f2bf(h_locB[i]);
      arrive_flag(hBf, cbg, t + 1);
    } else {
#pragma unroll
      for (int i = 0; i < 4; ++i)
        hfin[(size_t)(drowB + i) * HH + dcol] = h_locB[i];
    }
    if (t + 1 < TT) {
      short8 xf[8];
      load_xf<XM == 1>(xf, xbA, xfA32, t + 1);
      prime_x(xf, wz, wr, wh, azxA, arxA, ahxA);
      load_xf<XM == 1>(xf, xbB, xfB32, t + 1);
      prime_x(xf, wz, wr, wh, azxB, arxB, ahxB);
    }
  }
}

// out[b, c] = h_final[b,:] @ fc_w[:,c] + fc_b[c]
__global__ void fc_kernel(const float* __restrict__ hfin, const float* __restrict__ fw,
                          const float* __restrict__ fb, float* __restrict__ out) {
  int b = blockIdx.x;
  int tid = threadIdx.x;  // 64
  float p[10];
#pragma unroll
  for (int c = 0; c < 10; ++c) p[c] = 0.f;
  for (int k = tid; k < HH; k += 64) {
    float hv = hfin[(size_t)b * HH + k];
#pragma unroll
    for (int c = 0; c < 10; ++c) p[c] += hv * fw[k * 10 + c];
  }
#pragma unroll
  for (int c = 0; c < 10; ++c) {
    float v = p[c];
    for (int off = 32; off > 0; off >>= 1) v += __shfl_down(v, off);
    if (tid == 0) out[b * 10 + c] = v + fb[c];
  }
}

extern "C" void kernel_launch(void* const* d_in, const int* in_sizes, int n_in,
                              void* d_out, int out_size, void* d_ws, size_t ws_size,
                              hipStream_t stream) {
  const float* x = (const float*)d_in[0];
  const float* Wz_w = (const float*)d_in[1];
  const float* Wz_b = (const float*)d_in[2];
  const float* Wr_w = (const float*)d_in[3];
  const float* Wr_b = (const float*)d_in[4];
  const float* Wh_w = (const float*)d_in[5];
  const float* Wh_b = (const float*)d_in[6];
  const float* fc_w = (const float*)d_in[7];
  const float* fc_b = (const float*)d_in[8];

  char* ws = (char*)d_ws;
  short* wfrag = (short*)(ws + WFRAG_OFF);
  short* hbuf = (short*)(ws + HBUF_OFF);
  short* rhbuf = (short*)(ws + RHBUF_OFF);
  float* hfin = (float*)(ws + HFIN_OFF);
  int* ctrl = (int*)(ws + CTRL_OFF);
  short* xbase = (short*)(ws + XBASE_OFF);

  // h0 = 0, claim + done + flag arrays = 0 (EVERY launch)
  hipMemsetAsync(hbuf, 0, BB * HH * 2, stream);
  hipMemsetAsync(ctrl, 0, CTRL_BYTES, stream);

  prep_w<<<576, 256, 0, stream>>>(Wz_w, Wr_w, Wh_w, wfrag);

  if (ws_size >= WS_M2) {
    xproj_gemm<<<BB * TT / 64, 256, 0, stream>>>(x, wfrag, Wz_b, Wr_b, Wh_b, xbase);
    gru2p<<<256, 256, 0, stream>>>(xbase, wfrag, hbuf, rhbuf, hfin, ctrl);
  } else if (ws_size >= WS_M1) {
    xprep<<<(BB * TT * FF / 8) / 256, 256, 0, stream>>>(x, xbase);
    gru_kernel<1><<<256, 256, 0, stream>>>(xbase, wfrag, hbuf, rhbuf, hfin, ctrl,
                                           Wz_b, Wr_b, Wh_b);
  } else {
    gru_kernel<0><<<256, 256, 0, stream>>>(x, wfrag, hbuf, rhbuf, hfin, ctrl,
                                           Wz_b, Wr_b, Wh_b);
  }
  fc_kernel<<<BB, 64, 0, stream>>>(hfin, fc_w, fc_b, (float*)d_out);
}

// Round 14
// 2642.288 us; speedup vs baseline: 2.8105x; 2.0469x over previous
//
#include <hip/hip_runtime.h>

// GRU: B=256, T=512, F=256, H=512, C=10  (MI355X / gfx950)
// Round 14: cut serial phases/step 4 -> 2. 16 groups (2/XCD) x 8 WGs x 16
// rows, ONE row-set per WG. Per step: P1 (z,r -> rh exchange), P2 (h~ ->
// h exchange). Exchange = ack + flag + detect + tile load (LIC round trips,
// irreducible at agent scope); with only 2 phases/step the step wall drops
// from R9's 4x1.9us to ~2x2.2us. R9's proven staging kept: LDS tiles,
// batched agent-scope loads, loud burners, arrive-before-wait flags.

#define BB 256
#define TT 512
#define FF 256
#define HH 512
#define HX 1536
#define GROUP_WGS 8
#define NGRP 16

typedef short short8 __attribute__((ext_vector_type(8)));
typedef short short4v __attribute__((ext_vector_type(4)));
typedef float float4v __attribute__((ext_vector_type(4)));
typedef unsigned long long u64;
typedef unsigned short ushort;

// ws layout (bytes)
#define WFRAG_OFF 0
#define WFRAG_BYTES (32 * 3 * 24 * 64 * 8 * 2)            // 2,359,296
#define HBUF_OFF (WFRAG_OFF + WFRAG_BYTES)                 // bf16 h   [256][512]
#define RHBUF_OFF (HBUF_OFF + BB * HH * 2)                 // bf16 r*h [256][512]
#define HFIN_OFF (RHBUF_OFF + BB * HH * 2)                 // f32 h_final
#define CTRL_OFF (HFIN_OFF + BB * HH * 4)                  // claims + done + flags
#define CTRL_BYTES 16384
#define XBASE_OFF (CTRL_OFF + CTRL_BYTES)
#define XB_BYTES ((size_t)BB * TT * FF * 2)                // 67 MB (mode 1)
#define XPROJ_BYTES ((size_t)BB * TT * HX * 2)             // 402 MB (mode 2)
#define WS_M2 ((size_t)XBASE_OFF + XPROJ_BYTES)
#define WS_M1 ((size_t)XBASE_OFF + XB_BYTES)

__device__ __forceinline__ short f2bf(float f) {
  unsigned u = __builtin_bit_cast(unsigned, f);
  u += 0x7fffu + ((u >> 16) & 1u);            // RNE to bf16
  return (short)(u >> 16);
}
__device__ __forceinline__ float bf2f(ushort u) {
  return __builtin_bit_cast(float, (unsigned)u << 16);
}
__device__ __forceinline__ float sigm(float v) { return 1.0f / (1.0f + __expf(-v)); }
__device__ __forceinline__ float tanh_(float v) { return 2.0f / (1.0f + __expf(-2.0f * v)) - 1.0f; }
__device__ __forceinline__ float4v mfma_bf16(short8 a, short8 b, float4v c) {
  return __builtin_amdgcn_mfma_f32_16x16x32_bf16(a, b, c, 0, 0, 0);
}

// ---- weight prep: f32 [768][512] -> bf16 MFMA B-fragments ----
__global__ void prep_w(const float* __restrict__ Wz, const float* __restrict__ Wr,
                       const float* __restrict__ Wh, short* __restrict__ wfrag) {
  int id = blockIdx.x * 256 + threadIdx.x;     // 576*256 == 32*3*24*64
  int lane = id & 63;
  int rest = id >> 6;
  int kk = rest % 24;
  int gc = rest / 24;
  int g = gc % 3;
  int cb = gc / 3;
  if (cb >= 32) return;
  const float* W = (g == 0) ? Wz : ((g == 1) ? Wr : Wh);
  int n = cb * 16 + (lane & 15);
  int kbase = kk * 32 + (lane >> 4) * 8;
  short8 v;
#pragma unroll
  for (int j = 0; j < 8; ++j) v[j] = f2bf(W[(size_t)(kbase + j) * HH + n]);
  *(((short8*)wfrag) + id) = v;
}

// ---- x prep (mode 1 fallback): f32 -> bf16 ----
__global__ void xprep(const float* __restrict__ x, short* __restrict__ xb) {
  size_t i = (size_t)blockIdx.x * 256 + threadIdx.x;
  const float4v* src = (const float4v*)x;
  float4v a = src[i * 2], b = src[i * 2 + 1];
  short8 v;
  v[0] = f2bf(a[0]); v[1] = f2bf(a[1]); v[2] = f2bf(a[2]); v[3] = f2bf(a[3]);
  v[4] = f2bf(b[0]); v[5] = f2bf(b[1]); v[6] = f2bf(b[2]); v[7] = f2bf(b[3]);
  *(((short8*)xb) + i) = v;
}

// ---- xproj GEMM (mode 2): [BT,256] @ x-part weights -> bf16 [BT][3*512], bias folded ----
__global__ __launch_bounds__(256) void xproj_gemm(
    const float* __restrict__ x, const short* __restrict__ wfrag,
    const float* __restrict__ bz, const float* __restrict__ br,
    const float* __restrict__ bh, short* __restrict__ xp) {
  const int w = threadIdx.x >> 6, l = threadIdx.x & 63;
  const int l15 = l & 15, lhi = l >> 4;
  const size_t row0 = (size_t)blockIdx.x * 64 + w * 16;
  const float* xl = x + (row0 + l15) * FF + lhi * 8;
  short8 xf[8];
#pragma unroll
  for (int kx = 0; kx < 8; ++kx) {
    float4v a = *(const float4v*)(xl + kx * 32);
    float4v b2 = *(const float4v*)(xl + kx * 32 + 4);
    short8 v;
    v[0] = f2bf(a[0]); v[1] = f2bf(a[1]); v[2] = f2bf(a[2]); v[3] = f2bf(a[3]);
    v[4] = f2bf(b2[0]); v[5] = f2bf(b2[1]); v[6] = f2bf(b2[2]); v[7] = f2bf(b2[3]);
    xf[kx] = v;
  }
  const short8* wf = (const short8*)wfrag;
#pragma unroll 1
  for (int cb = 0; cb < 32; ++cb) {
#pragma unroll
    for (int g = 0; g < 3; ++g) {
      const float* bias = (g == 0) ? bz : ((g == 1) ? br : bh);
      float bv = bias[cb * 16 + l15];
      float4v acc = {bv, bv, bv, bv};
#pragma unroll
      for (int kx = 0; kx < 8; ++kx)
        acc = mfma_bf16(xf[kx], wf[((cb * 3 + g) * 24 + 16 + kx) * 64 + l], acc);
#pragma unroll
      for (int i = 0; i < 4; ++i)
        xp[(row0 + lhi * 4 + i) * HX + g * 512 + cb * 16 + l15] = f2bf(acc[i]);
    }
  }
}

// ---- flag primitives ----
// wait for all 32 wave-flags >= tgt, skipping our own slot (set just before)
__device__ __forceinline__ void wait_all(const int* fl, int tgt, int own) {
  const int li = threadIdx.x & 31;
  const int* p = fl + li;
  const bool self = (li == own);
  int tries = 0;
  for (;;) {
    int v = self ? tgt
                 : __hip_atomic_load(p, __ATOMIC_RELAXED, __HIP_MEMORY_SCOPE_AGENT);
    if (!__any(v < tgt)) break;
    if (++tries > 64) __builtin_amdgcn_s_sleep(1);
  }
}

// L1-bypassing 16B fragment load (two relaxed agent-scope u64 loads)
__device__ __forceinline__ short8 ld_frag(const short* p) {
  const u64* q = (const u64*)p;
  u64 lo = __hip_atomic_load(q, __ATOMIC_RELAXED, __HIP_MEMORY_SCOPE_AGENT);
  u64 hi = __hip_atomic_load(q + 1, __ATOMIC_RELAXED, __HIP_MEMORY_SCOPE_AGENT);
  short4v l4 = __builtin_bit_cast(short4v, lo);
  short4v h4 = __builtin_bit_cast(short4v, hi);
  return __builtin_shufflevector(l4, h4, 0, 1, 2, 3, 4, 5, 6, 7);
}

// ========= 1-set 2-phase XCD-local GRU, 16 groups (mode 2) =========
__global__ __launch_bounds__(256, 1) void gru1s(
    const short* __restrict__ xp, const short* __restrict__ wfrag,
    short* __restrict__ hbuf, short* __restrict__ rhbuf,
    float* __restrict__ hfin, int* __restrict__ ctrl) {
  __shared__ short lds[2 * 8192];   // buf0 = h tile, buf1 = rh tile
  __shared__ int s_slot, s_xcc;
  if (threadIdx.x == 0) {
    unsigned xcc;
    asm volatile("s_getreg_b32 %0, hwreg(HW_REG_XCC_ID)" : "=s"(xcc));
    xcc &= 7u;
    s_xcc = (int)xcc;
    s_slot = atomicAdd(ctrl + xcc * 16, 1);
  }
  __syncthreads();
  const int slot = s_slot;
  int* done = ctrl + 192;

  if (slot >= 2 * GROUP_WGS) {
    // burner (R9 loud cadence -- fastest measured)
    float a = (float)threadIdx.x;
    for (;;) {
#pragma unroll
      for (int i = 0; i < 512; ++i) a = __builtin_fmaf(a, 1.0000001f, 1.0f);
      asm volatile("" : "+v"(a));
      if (__hip_atomic_load(done, __ATOMIC_RELAXED, __HIP_MEMORY_SCOPE_AGENT) >= NGRP)
        break;
    }
    asm volatile("" :: "v"(a));
    return;
  }

  const int group = s_xcc * 2 + (slot >> 3);   // 0..15, XCD-local
  const int member = slot & 7;
  const int tid = threadIdx.x;
  const int w = tid >> 6, l = tid & 63, l15 = l & 15, lhi = l >> 4;
  const int cbg = member * 4 + w, jc = cbg * 16;
  const int rb = group * 16;                   // 16 rows per group
  const int dcol = jc + l15;

  // ---- weights (h-part) -> registers (192 VGPR) ----
  const short8* wf = (const short8*)wfrag;
  short8 wz[16], wr[16], wh[16];
#pragma unroll
  for (int kk = 0; kk < 16; ++kk) wz[kk] = wf[((cbg * 3 + 0) * 24 + kk) * 64 + l];
#pragma unroll
  for (int kk = 0; kk < 16; ++kk) wr[kk] = wf[((cbg * 3 + 1) * 24 + kk) * 64 + l];
#pragma unroll
  for (int kk = 0; kk < 16; ++kk) wh[kk] = wf[((cbg * 3 + 2) * 24 + kk) * 64 + l];

  const short* hS = hbuf + (size_t)rb * HH;    // 16KB tile bases
  const short* rhS = rhbuf + (size_t)rb * HH;

  const short* xpp[4];
#pragma unroll
  for (int i = 0; i < 4; ++i)
    xpp[i] = xp + (size_t)(rb + lhi * 4 + i) * TT * HX + dcol;

  int* fb = ctrl + 256 + group * 64;
  int* rhF = fb, * hF = fb + 32;

  float4v h_loc = {0, 0, 0, 0};
  float4v z;
  ushort nz[4], nr[4], nh[4];
  short8 Ra[4];

#define ACK asm volatile("s_waitcnt vmcnt(0)" ::: "memory")
#define ARR(FL, VAL)                                                         \
  { if (l == 0) __hip_atomic_store((FL) + cbg, VAL, __ATOMIC_RELAXED,        \
                                   __HIP_MEMORY_SCOPE_AGENT); }
#define DSW(BUF, R)                                                          \
  { _Pragma("unroll") for (int i_ = 0; i_ < 4; ++i_) {                       \
      int idx_ = w * 2048 + i_ * 512 + l * 8;                                \
      idx_ ^= ((w * 4 + i_) & 7) << 3;                                       \
      *(short8*)&lds[(BUF) * 8192 + idx_] = (R)[i_]; } }
#define LDG(R, GSRC)                                                         \
  { _Pragma("unroll") for (int i_ = 0; i_ < 4; ++i_)                         \
      (R)[i_] = ld_frag((GSRC) + w * 2048 + i_ * 512 + l * 8); }
#define DSFRAG(BUF, KK)                                                      \
  (*(const short8*)&lds[(BUF) * 8192 +                                       \
      (((l15 << 9) | ((KK) * 32 + lhi * 8)) ^ ((l15 & 7) << 3))])

  // prologue: buf0 = h(t=0) = zeros; xproj(t=0) staged
  for (int i = tid; i < 8192; i += 256) lds[i] = 0;
#pragma unroll
  for (int i = 0; i < 4; ++i) {
    nz[i] = *(const ushort*)(xpp[i]);
    nr[i] = *(const ushort*)(xpp[i] + 512);
    nh[i] = *(const ushort*)(xpp[i] + 1024);
  }

#pragma unroll 1
  for (int t = 0; t < TT; ++t) {
    const bool more = (t + 1 < TT);
    // ===== P1: consume buf0 (h), produce rh =====
    __syncthreads();                 // buf0 ready (prev P2's DSW / prologue)
    {
      float4v az, ar;
#pragma unroll
      for (int i = 0; i < 4; ++i) { az[i] = bf2f(nz[i]); ar[i] = bf2f(nr[i]); }
#pragma unroll
      for (int kk = 0; kk < 16; ++kk) {
        short8 a_ = DSFRAG(0, kk);
        az = mfma_bf16(a_, wz[kk], az);
        ar = mfma_bf16(a_, wr[kk], ar);
      }
#pragma unroll
      for (int i = 0; i < 4; ++i) {
        z[i] = sigm(az[i]);
        float rv = sigm(ar[i]);
        rhbuf[(size_t)(rb + lhi * 4 + i) * HH + dcol] = f2bf(rv * h_loc[i]);
      }
    }
    ACK;                             // rh stores acked at coherence point
    ARR(rhF, t + 1);
    wait_all(rhF, t + 1, cbg);       // all 32 waves' rh visible
    LDG(Ra, rhS);                    // full rh tile -> regs
    DSW(1, Ra);                      // -> buf1 (stalls on load return)

    // ===== P2: consume buf1 (rh), produce h =====
    __syncthreads();
    {
      float4v ah;
#pragma unroll
      for (int i = 0; i < 4; ++i) ah[i] = bf2f(nh[i]);
#pragma unroll
      for (int kk = 0; kk < 16; ++kk)
        ah = mfma_bf16(DSFRAG(1, kk), wh[kk], ah);
#pragma unroll
      for (int i = 0; i < 4; ++i) {
        float hv = tanh_(ah[i]);
        h_loc[i] = (1.0f - z[i]) * h_loc[i] + z[i] * hv;
        size_t dr = (size_t)(rb + lhi * 4 + i) * HH + dcol;
        if (more) hbuf[dr] = f2bf(h_loc[i]);
        else hfin[dr] = h_loc[i];
      }
    }
    if (more) {
      ACK;
      ARR(hF, t + 1);
      // xproj(t+1) prefetch: lands inside the wait, never stalls an ACK
      {
        size_t toff = (size_t)(t + 1) * HX;
#pragma unroll
        for (int i = 0; i < 4; ++i) {
          nz[i] = *(const ushort*)(xpp[i] + toff);
          nr[i] = *(const ushort*)(xpp[i] + toff + 512);
          nh[i] = *(const ushort*)(xpp[i] + toff + 1024);
        }
      }
      wait_all(hF, t + 1, cbg);
      LDG(Ra, hS);
      DSW(0, Ra);
    }
  }

  if (member == 0 && tid == 0)
    __hip_atomic_fetch_add(done, 1, __ATOMIC_RELAXED, __HIP_MEMORY_SCOPE_AGENT);
#undef ACK
#undef ARR
#undef DSW
#undef LDG
#undef DSFRAG
}

// ================== fallback (modes 1/0): R8 kernel ==================
__device__ __forceinline__ void wait_flags(const int* fl, int tgt) {
  const int* p = fl + (threadIdx.x & 31);
  for (;;) {
    int v = __hip_atomic_load(p, __ATOMIC_RELAXED, __HIP_MEMORY_SCOPE_AGENT);
    if (!__any(v < tgt)) break;
  }
}
__device__ __forceinline__ void arrive_flag(int* fl, int wid, int val) {
  asm volatile("s_waitcnt vmcnt(0)" ::: "memory");
  if ((threadIdx.x & 63) == 0)
    __hip_atomic_store(fl + wid, val, __ATOMIC_RELAXED, __HIP_MEMORY_SCOPE_AGENT);
}
__device__ __forceinline__ void gate_phase1(const short* hb_lane,
    const short8* wz, const short8* wr, float4v azx, float4v arx,
    float bz, float br, float4v& z, float4v& rr) {
  short8 a[16];
#pragma unroll
  for (int kk = 0; kk < 16; ++kk) a[kk] = ld_frag(hb_lane + kk * 32);
  float4v az = azx, ar = arx;
#pragma unroll
  for (int kk = 0; kk < 16; ++kk) {
    az = mfma_bf16(a[kk], wz[kk], az);
    ar = mfma_bf16(a[kk], wr[kk], ar);
  }
#pragma unroll
  for (int i = 0; i < 4; ++i) {
    z[i] = sigm(az[i] + bz);
    rr[i] = sigm(ar[i] + br);
  }
}
__device__ __forceinline__ float4v gate_phase2(const short* rh_lane,
    const short8* wh, float4v ahx, float bh, float4v z, float4v h_loc) {
  short8 a[16];
#pragma unroll
  for (int kk = 0; kk < 16; ++kk) a[kk] = ld_frag(rh_lane + kk * 32);
  float4v ah = ahx;
#pragma unroll
  for (int kk = 0; kk < 16; ++kk)
    ah = mfma_bf16(a[kk], wh[kk], ah);
  float4v hn;
#pragma unroll
  for (int i = 0; i < 4; ++i) {
    float hv = tanh_(ah[i] + bh);
    hn[i] = (1.0f - z[i]) * h_loc[i] + z[i] * hv;
  }
  return hn;
}
template <bool XB>
__device__ __forceinline__ void load_xf(short8 (&xf)[8], const short* xb_l,
                                        const float* xf_l, int t) {
#pragma unroll
  for (int kx = 0; kx < 8; ++kx) {
    if constexpr (XB) {
      xf[kx] = *(const short8*)(xb_l + (size_t)t * FF + kx * 32);
    } else {
      const float* xl = xf_l + (size_t)t * FF;
      float4v a = *(const float4v*)(xl + kx * 32);
      float4v b2 = *(const float4v*)(xl + kx * 32 + 4);
      short8 v;
      v[0] = f2bf(a[0]); v[1] = f2bf(a[1]); v[2] = f2bf(a[2]); v[3] = f2bf(a[3]);
      v[4] = f2bf(b2[0]); v[5] = f2bf(b2[1]); v[6] = f2bf(b2[2]); v[7] = f2bf(b2[3]);
      xf[kx] = v;
    }
  }
}
__device__ __forceinline__ void prime_x(const short8 (&xf)[8],
    const short8* wz, const short8* wr, const short8* wh,
    float4v& azx, float4v& arx, float4v& ahx) {
  azx = (float4v){0.f, 0.f, 0.f, 0.f};
  arx = (float4v){0.f, 0.f, 0.f, 0.f};
  ahx = (float4v){0.f, 0.f, 0.f, 0.f};
#pragma unroll
  for (int kx = 0; kx < 8; ++kx) {
    azx = mfma_bf16(xf[kx], wz[16 + kx], azx);
    arx = mfma_bf16(xf[kx], wr[16 + kx], arx);
    ahx = mfma_bf16(xf[kx], wh[16 + kx], ahx);
  }
}
template <int XM>
__global__ __launch_bounds__(256, 1) void gru_kernel(
    const void* __restrict__ xv, const short* __restrict__ wfrag,
    short* __restrict__ hbuf, short* __restrict__ rhbuf,
    float* __restrict__ hfin, int* __restrict__ ctrl,
    const float* __restrict__ bzv, const float* __restrict__ brv,
    const float* __restrict__ bhv) {
  __shared__ int s_slot, s_xcc;
  if (threadIdx.x == 0) {
    unsigned xcc;
    asm volatile("s_getreg_b32 %0, hwreg(HW_REG_XCC_ID)" : "=s"(xcc));
    xcc &= 7u;
    s_xcc = (int)xcc;
    s_slot = atomicAdd(ctrl + xcc * 16, 1);
  }
  __syncthreads();
  const int slot = s_slot;
  if (slot >= GROUP_WGS) return;
  const int group = s_xcc;
  const int member = slot;
  const int tid = threadIdx.x;
  const int w = tid >> 6;
  const int l = tid & 63;
  const int l15 = l & 15;
  const int lhi = l >> 4;
  const int cbg = member * 4 + w;
  const int jc = cbg * 16;
  const int rbA = group * 32;
  const int rbB = rbA + 16;
  const short8* wf = (const short8*)wfrag;
  short8 wz[24], wr[24], wh[24];
#pragma unroll
  for (int kk = 0; kk < 24; ++kk) wz[kk] = wf[((cbg * 3 + 0) * 24 + kk) * 64 + l];
#pragma unroll
  for (int kk = 0; kk < 24; ++kk) wr[kk] = wf[((cbg * 3 + 1) * 24 + kk) * 64 + l];
#pragma unroll
  for (int kk = 0; kk < 24; ++kk) wh[kk] = wf[((cbg * 3 + 2) * 24 + kk) * 64 + l];
  const float bz = bzv[jc + l15], br = brv[jc + l15], bh = bhv[jc + l15];
  const int drowA = rbA + lhi * 4, drowB = rbB + lhi * 4;
  const int dcol = jc + l15;
  const short* hbA = hbuf + (size_t)(rbA + l15) * HH + lhi * 8;
  const short* hbB = hbuf + (size_t)(rbB + l15) * HH + lhi * 8;
  const short* rhA = rhbuf + (size_t)(rbA + l15) * HH + lhi * 8;
  const short* rhB = rhbuf + (size_t)(rbB + l15) * HH + lhi * 8;
  const float* xfA32 = (XM == 0) ? ((const float*)xv + (size_t)(rbA + l15) * TT * FF + lhi * 8) : nullptr;
  const float* xfB32 = (XM == 0) ? ((const float*)xv + (size_t)(rbB + l15) * TT * FF + lhi * 8) : nullptr;
  const short* xbA = (XM == 1) ? ((const short*)xv + (size_t)(rbA + l15) * TT * FF + lhi * 8) : nullptr;
  const short* xbB = (XM == 1) ? ((const short*)xv + (size_t)(rbB + l15) * TT * FF + lhi * 8) : nullptr;
  float4v h_locA = {0.f, 0.f, 0.f, 0.f}, h_locB = {0.f, 0.f, 0.f, 0.f};
  int* fb = ctrl + 256 + 1024 + group * 256;
  int* rhAf = fb, * rhBf = fb + 32, * hAf = fb + 64, * hBf = fb + 96;
  float4v azxA, arxA, ahxA, azxB, arxB, ahxB;
  {
    short8 xf[8];
    load_xf<XM == 1>(xf, xbA, xfA32, 0);
    prime_x(xf, wz, wr, wh, azxA, arxA, ahxA);
    load_xf<XM == 1>(xf, xbB, xfB32, 0);
    prime_x(xf, wz, wr, wh, azxB, arxB, ahxB);
  }
#pragma unroll 1
  for (int t = 0; t < TT; ++t) {
    if (t) wait_flags(hAf, t);
    float4v zA, rrA;
    gate_phase1(hbA, wz, wr, azxA, arxA, bz, br, zA, rrA);
#pragma unroll
    for (int i = 0; i < 4; ++i)
      rhbuf[(size_t)(drowA + i) * HH + dcol] = f2bf(rrA[i] * h_locA[i]);
    arrive_flag(rhAf, cbg, t + 1);
    if (t) wait_flags(hBf, t);
    float4v zB, rrB;
    gate_phase1(hbB, wz, wr, azxB, arxB, bz, br, zB, rrB);
#pragma unroll
    for (int i = 0; i < 4; ++i)
      rhbuf[(size_t)(drowB + i) * HH + dcol] = f2bf(rrB[i] * h_locB[i]);
    arrive_flag(rhBf, cbg, t + 1);
    wait_flags(rhAf, t + 1);
    h_locA = gate_phase2(rhA, wh, ahxA, bh, zA, h_locA);
    if (t + 1 < TT) {
#pragma unroll
      for (int i = 0; i < 4; ++i)
        hbuf[(size_t)(drowA + i) * HH + dcol] = f2bf(h_locA[i]);
      arrive_flag(hAf, cbg, t + 1);
    } else {
#pragma unroll
      for (int i = 0; i < 4; ++i)
        hfin[(size_t)(drowA + i) * HH + dcol] = h_locA[i];
    }
    wait_flags(rhBf, t + 1);
    h_locB = gate_phase2(rhB, wh, ahxB, bh, zB, h_locB);
    if (t + 1 < TT) {
#pragma unroll
      for (int i = 0; i < 4; ++i)
        hbuf[(size_t)(drowB + i) * HH + dcol] = f2bf(h_locB[i]);
      arrive_flag(hBf, cbg, t + 1);
    } else {
#pragma unroll
      for (int i = 0; i < 4; ++i)
        hfin[(size_t)(drowB + i) * HH + dcol] = h_locB[i];
    }
    if (t + 1 < TT) {
      short8 xf[8];
      load_xf<XM == 1>(xf, xbA, xfA32, t + 1);
      prime_x(xf, wz, wr, wh, azxA, arxA, ahxA);
      load_xf<XM == 1>(xf, xbB, xfB32, t + 1);
      prime_x(xf, wz, wr, wh, azxB, arxB, ahxB);
    }
  }
}

// out[b, c] = h_final[b,:] @ fc_w[:,c] + fc_b[c]
__global__ void fc_kernel(const float* __restrict__ hfin, const float* __restrict__ fw,
                          const float* __restrict__ fb, float* __restrict__ out) {
  int b = blockIdx.x;
  int tid = threadIdx.x;  // 64
  float p[10];
#pragma unroll
  for (int c = 0; c < 10; ++c) p[c] = 0.f;
  for (int k = tid; k < HH; k += 64) {
    float hv = hfin[(size_t)b * HH + k];
#pragma unroll
    for (int c = 0; c < 10; ++c) p[c] += hv * fw[k * 10 + c];
  }
#pragma unroll
  for (int c = 0; c < 10; ++c) {
    float v = p[c];
    for (int off = 32; off > 0; off >>= 1) v += __shfl_down(v, off);
    if (tid == 0) out[b * 10 + c] = v + fb[c];
  }
}

extern "C" void kernel_launch(void* const* d_in, const int* in_sizes, int n_in,
                              void* d_out, int out_size, void* d_ws, size_t ws_size,
                              hipStream_t stream) {
  const float* x = (const float*)d_in[0];
  const float* Wz_w = (const float*)d_in[1];
  const float* Wz_b = (const float*)d_in[2];
  const float* Wr_w = (const float*)d_in[3];
  const float* Wr_b = (const float*)d_in[4];
  const float* Wh_w = (const float*)d_in[5];
  const float* Wh_b = (const float*)d_in[6];
  const float* fc_w = (const float*)d_in[7];
  const float* fc_b = (const float*)d_in[8];

  char* ws = (char*)d_ws;
  short* wfrag = (short*)(ws + WFRAG_OFF);
  short* hbuf = (short*)(ws + HBUF_OFF);
  short* rhbuf = (short*)(ws + RHBUF_OFF);
  float* hfin = (float*)(ws + HFIN_OFF);
  int* ctrl = (int*)(ws + CTRL_OFF);
  short* xbase = (short*)(ws + XBASE_OFF);

  // h0 = 0, claim + done + flag arrays = 0 (EVERY launch)
  hipMemsetAsync(hbuf, 0, BB * HH * 2, stream);
  hipMemsetAsync(ctrl, 0, CTRL_BYTES, stream);

  prep_w<<<576, 256, 0, stream>>>(Wz_w, Wr_w, Wh_w, wfrag);

  if (ws_size >= WS_M2) {
    xproj_gemm<<<BB * TT / 64, 256, 0, stream>>>(x, wfrag, Wz_b, Wr_b, Wh_b, xbase);
    gru1s<<<256, 256, 0, stream>>>(xbase, wfrag, hbuf, rhbuf, hfin, ctrl);
  } else if (ws_size >= WS_M1) {
    xprep<<<(BB * TT * FF / 8) / 256, 256, 0, stream>>>(x, xbase);
    gru_kernel<1><<<256, 256, 0, stream>>>(xbase, wfrag, hbuf, rhbuf, hfin, ctrl,
                                           Wz_b, Wr_b, Wh_b);
  } else {
    gru_kernel<0><<<256, 256, 0, stream>>>(x, wfrag, hbuf, rhbuf, hfin, ctrl,
                                           Wz_b, Wr_b, Wh_b);
  }
  fc_kernel<<<BB, 64, 0, stream>>>(hfin, fc_w, fc_b, (float*)d_out);
}